// Round 1
// baseline (293.643 us; speedup 1.0000x reference)
//
#include <hip/hip_runtime.h>
#include <math.h>

#define NSLOT 256
#define HWN   16384
#define D_    256
#define BB    4
#define NSEL  768
#define NPOS  512
#define NHEAD 8

// ---------------- Kernel A: per-slot top-768 stable select ----------------
__global__ __launch_bounds__(256) void topk_kernel(const float* __restrict__ curio,
                                                   int* __restrict__ feat_sel) {
  __shared__ unsigned int hist[4096];
  __shared__ unsigned int chunkSum[256];
  __shared__ unsigned int chunkSuf[256];
  __shared__ unsigned long long skey[2048];
  __shared__ int sBstar;
  __shared__ unsigned int sCount;
  int s = blockIdx.x;
  int t = threadIdx.x;
  const float* row = curio + (size_t)s * HWN;

  for (int i = t; i < 4096; i += 256) hist[i] = 0;
  __syncthreads();
  for (int j = t; j < HWN; j += 256) {
    unsigned int bits = __float_as_uint(row[j]);   // values in [0,1): bits monotone
    atomicAdd(&hist[bits >> 18], 1u);
  }
  __syncthreads();
  {
    unsigned int cs = 0;
    int base = t * 16;
    for (int i = 0; i < 16; i++) cs += hist[base + i];
    chunkSum[t] = cs;
  }
  __syncthreads();
  if (t == 0) {
    unsigned int run = 0;
    for (int c = 255; c >= 0; c--) { chunkSuf[c] = run; run += chunkSum[c]; }
    sCount = 0;
  }
  __syncthreads();
  {
    unsigned int local = chunkSuf[t];
    if (local < NSEL && local + chunkSum[t] >= NSEL) {
      for (int b = t * 16 + 15; b >= t * 16; b--) {
        unsigned int c = hist[b];
        if (local + c >= NSEL) { sBstar = b; break; }
        local += c;
      }
    }
  }
  __syncthreads();
  int bstar = sBstar;
  for (int j = t; j < HWN; j += 256) {
    unsigned int bits = __float_as_uint(row[j]);
    if ((int)(bits >> 18) >= bstar) {
      unsigned int pos = atomicAdd(&sCount, 1u);
      if (pos < 2048)
        skey[pos] = ((unsigned long long)bits << 14) | (unsigned long long)(16383 - j);
    }
  }
  __syncthreads();
  unsigned int M = sCount;
  for (int i = t; i < 2048; i += 256) if (i >= M) skey[i] = 0ull;
  // bitonic sort descending (value desc, index asc == stable argsort(-flat))
  for (int k = 2; k <= 2048; k <<= 1) {
    for (int j2 = k >> 1; j2 > 0; j2 >>= 1) {
      __syncthreads();
      for (int i = t; i < 2048; i += 256) {
        int l = i ^ j2;
        if (l > i) {
          unsigned long long a = skey[i], b = skey[l];
          bool dir = ((i & k) == 0);
          if ((a < b) == dir) { skey[i] = b; skey[l] = a; }
        }
      }
    }
  }
  __syncthreads();
  for (int r = t; r < NSEL; r += 256)
    feat_sel[s * NSEL + r] = 16383 - (int)(skey[r] & 16383ull);
}

// ---------------- Kernel B: q projection + qk = Wk^T q (per slot) ----------------
__global__ __launch_bounds__(256) void qproj_kernel(const float* __restrict__ slots,
                                                    const float* __restrict__ ipw,
                                                    const float* __restrict__ ipb,
                                                    float* __restrict__ qk_g,
                                                    float* __restrict__ qbk_g) {
  __shared__ float srow[D_];
  __shared__ float qrow[D_];
  int s = blockIdx.x, t = threadIdx.x;
  srow[t] = slots[s * D_ + t];
  __syncthreads();
  {
    const float* wq = ipw + (size_t)t * D_;
    float acc = ipb[t];
    for (int d = 0; d < D_; d++) acc += srow[d] * wq[d];
    qrow[t] = acc * 0.17677669529663689f;  // 1/sqrt(32)
  }
  __syncthreads();
  for (int h = 0; h < NHEAD; h++) {
    const float* wkbase = ipw + (size_t)(D_ + h * 32) * D_ + t;
    float a = 0.f;
    for (int e = 0; e < 32; e++) a += qrow[h * 32 + e] * wkbase[(size_t)e * D_];
    qk_g[((size_t)s * NHEAD + h) * D_ + t] = a;
  }
  if (t < NHEAD) {
    float a = 0.f;
    for (int e = 0; e < 32; e++) a += qrow[t * 32 + e] * ipb[D_ + t * 32 + e];
    qbk_g[s * NHEAD + t] = a;
  }
}

// ---------------- Kernel C: fused gather + aff + softmax + norm_aff + PV ----------------
__global__ __launch_bounds__(512) void attn_kernel(
    const float* __restrict__ features, const float* __restrict__ posenc,
    const int* __restrict__ batch_idx, const int* __restrict__ feat_sel,
    const float* __restrict__ qk_g, const float* __restrict__ qbk_g,
    const float* __restrict__ ipw, const float* __restrict__ ipb,
    float* __restrict__ out_attn, float* __restrict__ norm_aff) {
  __shared__ float qk[NHEAD][D_];
  __shared__ float aff[NHEAD][NSEL];
  __shared__ float wgt[NHEAD][NPOS];
  __shared__ float fbar[NHEAD][D_];
  __shared__ float aff2s[NSEL];
  __shared__ float qbk_s[NHEAD];
  __shared__ float redS[NHEAD], redQ[NHEAD];
  int s = blockIdx.x;
  int t = threadIdx.x;
  int wave = t >> 6, lane = t & 63;

  for (int i = t; i < NHEAD * D_; i += 512) ((float*)qk)[i] = qk_g[(size_t)s * (NHEAD * D_) + i];
  if (t < NHEAD) qbk_s[t] = qbk_g[s * NHEAD + t];
  int bi = batch_idx[s];
  const int* fsel = feat_sel + s * NSEL;
  __syncthreads();

  float4 qkr[NHEAD];
#pragma unroll
  for (int h = 0; h < NHEAD; h++) qkr[h] = *(const float4*)&qk[h][lane * 4];

  // pass 1: aff[h][n] = (f+p)[n] . qk[h]  (wave-per-row, coalesced 1KB gathers)
  for (int n = wave; n < NSEL; n += 8) {
    int idx = fsel[n];
    size_t base = ((size_t)idx * BB + bi) * D_ + (size_t)(lane * 4);
    const float4 fv = *(const float4*)(features + base);
    const float4 pv = *(const float4*)(posenc + base);
    float kx = fv.x + pv.x, ky = fv.y + pv.y, kz = fv.z + pv.z, kw = fv.w + pv.w;
    float p[NHEAD];
#pragma unroll
    for (int h = 0; h < NHEAD; h++)
      p[h] = kx * qkr[h].x + ky * qkr[h].y + kz * qkr[h].z + kw * qkr[h].w;
#pragma unroll
    for (int off = 32; off >= 1; off >>= 1) {
#pragma unroll
      for (int h = 0; h < NHEAD; h++) p[h] += __shfl_xor(p[h], off, 64);
    }
    if (lane == 0) {
      aff[0][n] = p[0] + qbk_s[0];
      aff[1][n] = p[1] + qbk_s[1];
      aff[2][n] = p[2] + qbk_s[2];
      aff[3][n] = p[3] + qbk_s[3];
      aff[4][n] = p[4] + qbk_s[4];
      aff[5][n] = p[5] + qbk_s[5];
      aff[6][n] = p[6] + qbk_s[6];
      aff[7][n] = p[7] + qbk_s[7];
    }
  }
  __syncthreads();

  // softmax over n<512, wave == head
  {
    int h = wave;
    float m = -3.0e38f;
    for (int n = lane; n < NPOS; n += 64) m = fmaxf(m, aff[h][n]);
#pragma unroll
    for (int off = 32; off >= 1; off >>= 1) m = fmaxf(m, __shfl_xor(m, off, 64));
    float sum = 0.f;
    for (int n = lane; n < NPOS; n += 64) {
      float e = __expf(aff[h][n] - m);
      wgt[h][n] = e;
      sum += e;
    }
#pragma unroll
    for (int off = 32; off >= 1; off >>= 1) sum += __shfl_xor(sum, off, 64);
    float inv = 1.0f / sum;
    for (int n = lane; n < NPOS; n += 64) wgt[h][n] *= inv;
  }
  __syncthreads();

  // aff2 = mean over heads; layernorm over 768 -> norm_aff[n*256+s]
  for (int n = t; n < NSEL; n += 512) {
    float a = 0.f;
#pragma unroll
    for (int h = 0; h < NHEAD; h++) a += aff[h][n];
    aff2s[n] = a * (1.0f / NHEAD);
  }
  __syncthreads();
  {
    float ls = 0.f, lq = 0.f;
    for (int n = t; n < NSEL; n += 512) { float v = aff2s[n]; ls += v; lq += v * v; }
#pragma unroll
    for (int off = 32; off >= 1; off >>= 1) { ls += __shfl_xor(ls, off, 64); lq += __shfl_xor(lq, off, 64); }
    if (lane == 0) { redS[wave] = ls; redQ[wave] = lq; }
  }
  __syncthreads();
  {
    float tots = 0.f, totq = 0.f;
#pragma unroll
    for (int w2 = 0; w2 < NHEAD; w2++) { tots += redS[w2]; totq += redQ[w2]; }
    float mean = tots * (1.0f / NSEL);
    float var = totq * (1.0f / NSEL) - mean * mean;
    float rstd = rsqrtf(var + 1e-5f);
    for (int n = t; n < NSEL; n += 512)
      norm_aff[(size_t)n * NSLOT + s] = (aff2s[n] - mean) * rstd;
  }

  // pass 2: fbar[h][d] = sum_{n<512} wgt[h][n] * f[n][d]   (wave == head)
  {
    int h = wave;
    float ax = 0.f, ay = 0.f, az = 0.f, aw = 0.f;
    for (int n = 0; n < NPOS; n++) {
      int idx = fsel[n];
      size_t base = ((size_t)idx * BB + bi) * D_ + (size_t)(lane * 4);
      const float4 fv = *(const float4*)(features + base);
      float w = wgt[h][n];
      ax += w * fv.x; ay += w * fv.y; az += w * fv.z; aw += w * fv.w;
    }
    fbar[h][lane * 4 + 0] = ax;
    fbar[h][lane * 4 + 1] = ay;
    fbar[h][lane * 4 + 2] = az;
    fbar[h][lane * 4 + 3] = aw;
  }
  __syncthreads();

  // out[s, t] = Wv[t,:] . fbar[t>>5] + bv[t]
  if (t < D_) {
    int h = t >> 5;
    const float* wv = ipw + (size_t)(2 * D_ + t) * D_;
    float a = ipb[2 * D_ + t];
    for (int d = 0; d < D_; d++) a += fbar[h][d] * wv[d];
    out_attn[s * D_ + t] = a;
  }
}

// ---------------- Kernel D: out-proj + residual + layernorm ----------------
__global__ __launch_bounds__(256) void epilogue_kernel(
    const float* __restrict__ slots, const float* __restrict__ out_attn,
    const float* __restrict__ wout, const float* __restrict__ bout,
    const float* __restrict__ lnw, const float* __restrict__ lnb,
    float* __restrict__ slots_new) {
  __shared__ float o[D_];
  __shared__ float redS[4], redQ[4];
  int s = blockIdx.x, t = threadIdx.x;
  int wave = t >> 6, lane = t & 63;
  o[t] = out_attn[s * D_ + t];
  __syncthreads();
  const float* w = wout + (size_t)t * D_;
  float a = bout[t];
  for (int d = 0; d < D_; d++) a += o[d] * w[d];
  float v = slots[s * D_ + t] + a;
  float ls = v, lq = v * v;
#pragma unroll
  for (int off = 32; off >= 1; off >>= 1) { ls += __shfl_xor(ls, off, 64); lq += __shfl_xor(lq, off, 64); }
  if (lane == 0) { redS[wave] = ls; redQ[wave] = lq; }
  __syncthreads();
  float tots = redS[0] + redS[1] + redS[2] + redS[3];
  float totq = redQ[0] + redQ[1] + redQ[2] + redQ[3];
  float mean = tots * (1.0f / D_);
  float var = totq * (1.0f / D_) - mean * mean;
  float rstd = rsqrtf(var + 1e-5f);
  slots_new[s * D_ + t] = (v - mean) * rstd * lnw[t] + lnb[t];
}

extern "C" void kernel_launch(void* const* d_in, const int* in_sizes, int n_in,
                              void* d_out, int out_size, void* d_ws, size_t ws_size,
                              hipStream_t stream) {
  const float* slots    = (const float*)d_in[0];
  const float* features = (const float*)d_in[1];
  const float* posenc   = (const float*)d_in[2];
  const float* curio    = (const float*)d_in[3];
  const int*   batch_idx= (const int*)d_in[4];
  const float* ipw      = (const float*)d_in[5];
  const float* ipb      = (const float*)d_in[6];
  const float* wout     = (const float*)d_in[7];
  const float* bout     = (const float*)d_in[8];
  const float* lnw      = (const float*)d_in[9];
  const float* lnb      = (const float*)d_in[10];

  char* ws = (char*)d_ws;
  int*   feat_sel = (int*)ws;                                   // 256*768*4   = 786432 B
  float* qk       = (float*)(ws + 786432);                      // 256*8*256*4 = 2097152 B
  float* qbk      = (float*)(ws + 786432 + 2097152);            // 256*8*4     = 8192 B
  float* out_attn = (float*)(ws + 786432 + 2097152 + 8192);     // 256*256*4   = 262144 B
  float* out_f    = (float*)d_out;                              // [0,65536) slots_new, [65536,262144) norm_aff

  topk_kernel<<<NSLOT, 256, 0, stream>>>(curio, feat_sel);
  qproj_kernel<<<NSLOT, 256, 0, stream>>>(slots, ipw, ipb, qk, qbk);
  attn_kernel<<<NSLOT, 512, 0, stream>>>(features, posenc, batch_idx, feat_sel,
                                         qk, qbk, ipw, ipb, out_attn, out_f + 65536);
  epilogue_kernel<<<NSLOT, 256, 0, stream>>>(slots, out_attn, wout, bout, lnw, lnb, out_f);
}

// Round 2
// 190.402 us; speedup vs baseline: 1.5422x; 1.5422x over previous
//
#include <hip/hip_runtime.h>
#include <math.h>

#define NSLOT 256
#define HWN   16384
#define D_    256
#define BB    4
#define NSEL  768
#define NPOS  512
#define NHEAD 8
#define NWAVE 16

// Reduce 8 per-lane values over all 64 lanes simultaneously.
// Returns: full 64-lane sum of p[h], where h = (lane>>3)&7 for this lane.
__device__ inline float reduce8x64(const float p[8], int lane) {
  float v[4];
#pragma unroll
  for (int h = 0; h < 4; h++) {
    float keep = (lane & 32) ? p[h + 4] : p[h];
    float send = (lane & 32) ? p[h] : p[h + 4];
    v[h] = keep + __shfl_xor(send, 32, 64);
  }
  float w[2];
#pragma unroll
  for (int h = 0; h < 2; h++) {
    float keep = (lane & 16) ? v[h + 2] : v[h];
    float send = (lane & 16) ? v[h] : v[h + 2];
    w[h] = keep + __shfl_xor(send, 16, 64);
  }
  float r;
  {
    float keep = (lane & 8) ? w[1] : w[0];
    float send = (lane & 8) ? w[0] : w[1];
    r = keep + __shfl_xor(send, 8, 64);
  }
  r += __shfl_xor(r, 4, 64);
  r += __shfl_xor(r, 2, 64);
  r += __shfl_xor(r, 1, 64);
  return r;
}

// ---------------- Kernel A: per-slot top-768 stable select (1024 thr) ----------------
__global__ __launch_bounds__(1024) void topk_kernel(const float* __restrict__ curio,
                                                    int* __restrict__ feat_sel) {
  __shared__ unsigned int hist[4096];
  __shared__ unsigned int wsum[16];
  __shared__ unsigned long long skey[2048];
  __shared__ int sBstar;
  __shared__ unsigned int sCount;
  int s = blockIdx.x;
  int t = threadIdx.x;
  int wave = t >> 6, lane = t & 63;
  const float* row = curio + (size_t)s * HWN;

  for (int i = t; i < 4096; i += 1024) hist[i] = 0;
  if (t == 0) sCount = 0;
  __syncthreads();
  for (int j = t; j < HWN; j += 1024) {
    unsigned int bits = __float_as_uint(row[j]);   // values in [0,1): bits monotone
    atomicAdd(&hist[bits >> 18], 1u);
  }
  __syncthreads();
  // 4 bins per thread; suffix-sum of chunk counts (descending-bin order)
  unsigned int cs = hist[t * 4] + hist[t * 4 + 1] + hist[t * 4 + 2] + hist[t * 4 + 3];
  unsigned int v = cs;
#pragma unroll
  for (int off = 1; off < 64; off <<= 1) {
    unsigned int u = __shfl_down(v, off, 64);
    if (lane + off < 64) v += u;       // v = sum over lanes >= lane (this wave)
  }
  if (lane == 0) wsum[wave] = v;
  __syncthreads();
  unsigned int above = 0;
  for (int w2 = wave + 1; w2 < 16; w2++) above += wsum[w2];
  unsigned int sufAfter = above + (v - cs);  // count in chunks strictly after mine
  if (sufAfter < NSEL && sufAfter + cs >= NSEL) {
    unsigned int local = sufAfter;
    for (int b = t * 4 + 3; b >= t * 4; b--) {
      unsigned int c = hist[b];
      if (local + c >= NSEL) { sBstar = b; break; }
      local += c;
    }
  }
  __syncthreads();
  int bstar = sBstar;
  for (int j = t; j < HWN; j += 1024) {
    unsigned int bits = __float_as_uint(row[j]);
    if ((int)(bits >> 18) >= bstar) {
      unsigned int pos = atomicAdd(&sCount, 1u);
      if (pos < 2048)
        skey[pos] = ((unsigned long long)bits << 14) | (unsigned long long)(16383 - j);
    }
  }
  __syncthreads();
  unsigned int M = sCount;
  int SZ = (M <= 1024) ? 1024 : 2048;
  for (int i = t; i < SZ; i += 1024) if (i >= (int)M) skey[i] = 0ull;
  // bitonic sort descending (value desc, index asc == stable argsort(-flat))
  for (int k = 2; k <= SZ; k <<= 1) {
    for (int j2 = k >> 1; j2 > 0; j2 >>= 1) {
      __syncthreads();
      for (int i = t; i < SZ; i += 1024) {
        int l = i ^ j2;
        if (l > i) {
          unsigned long long a = skey[i], b = skey[l];
          bool dir = ((i & k) == 0);
          if ((a < b) == dir) { skey[i] = b; skey[l] = a; }
        }
      }
    }
  }
  __syncthreads();
  for (int r = t; r < NSEL; r += 1024)
    feat_sel[s * NSEL + r] = 16383 - (int)(skey[r] & 16383ull);
}

// ---------------- Kernel B: q projection + qk = Wk^T q (per slot) ----------------
__global__ __launch_bounds__(256) void qproj_kernel(const float* __restrict__ slots,
                                                    const float* __restrict__ ipw,
                                                    const float* __restrict__ ipb,
                                                    float* __restrict__ qk_g,
                                                    float* __restrict__ qbk_g) {
  __shared__ float srow[D_];
  __shared__ float qrow[D_];
  int s = blockIdx.x, t = threadIdx.x;
  srow[t] = slots[s * D_ + t];
  __syncthreads();
  {
    const float* wq = ipw + (size_t)t * D_;
    float acc = ipb[t];
    for (int d = 0; d < D_; d++) acc += srow[d] * wq[d];
    qrow[t] = acc * 0.17677669529663689f;  // 1/sqrt(32)
  }
  __syncthreads();
  for (int h = 0; h < NHEAD; h++) {
    const float* wkbase = ipw + (size_t)(D_ + h * 32) * D_ + t;
    float a = 0.f;
    for (int e = 0; e < 32; e++) a += qrow[h * 32 + e] * wkbase[(size_t)e * D_];
    qk_g[((size_t)s * NHEAD + h) * D_ + t] = a;
  }
  if (t < NHEAD) {
    float a = 0.f;
    for (int e = 0; e < 32; e++) a += qrow[t * 32 + e] * ipb[D_ + t * 32 + e];
    qbk_g[s * NHEAD + t] = a;
  }
}

// ---------------- Kernel C: fused gather + aff + softmax + norm_aff + PV (1024 thr) ----------------
__global__ __launch_bounds__(1024) void attn_kernel(
    const float* __restrict__ features, const float* __restrict__ posenc,
    const int* __restrict__ batch_idx, const int* __restrict__ feat_sel,
    const float* __restrict__ qk_g, const float* __restrict__ qbk_g,
    const float* __restrict__ ipw, const float* __restrict__ ipb,
    float* __restrict__ out_attn, float* __restrict__ norm_aff) {
  __shared__ float qk[NHEAD][D_];        // 8 KB
  __shared__ float aff[NHEAD][NSEL];     // 24 KB
  __shared__ float wgt[NHEAD][NPOS];     // 16 KB (unnormalized exp); reused as partials later
  __shared__ float fbar[NHEAD][D_];      // 8 KB
  __shared__ float aff2s[NSEL];          // 3 KB
  __shared__ float qbk_s[NHEAD];
  __shared__ float sinv[NHEAD];
  __shared__ float redS[NWAVE], redQ[NWAVE];
  int s = blockIdx.x;
  int t = threadIdx.x;
  int wave = t >> 6, lane = t & 63;

  for (int i = t; i < NHEAD * D_; i += 1024) {
    ((float*)qk)[i] = qk_g[(size_t)s * (NHEAD * D_) + i];
    ((float*)fbar)[i] = 0.f;
  }
  if (t < NHEAD) qbk_s[t] = qbk_g[s * NHEAD + t];
  int bi = batch_idx[s];
  const int* fsel = feat_sel + s * NSEL;
  __syncthreads();

  float4 qkr[NHEAD];
#pragma unroll
  for (int h = 0; h < NHEAD; h++) qkr[h] = *(const float4*)&qk[h][lane * 4];

  // pass 1: aff[h][n] = (f+p)[n] . qk[h]  (wave-per-row, 2-row unroll)
  for (int n = wave; n < NSEL; n += 2 * NWAVE) {
    int n2 = n + NWAVE;
    int idxA = fsel[n], idxB = fsel[n2];
    size_t baseA = ((size_t)idxA * BB + bi) * D_ + (size_t)(lane * 4);
    size_t baseB = ((size_t)idxB * BB + bi) * D_ + (size_t)(lane * 4);
    const float4 fA = *(const float4*)(features + baseA);
    const float4 pA4 = *(const float4*)(posenc + baseA);
    const float4 fB = *(const float4*)(features + baseB);
    const float4 pB4 = *(const float4*)(posenc + baseB);
    float kAx = fA.x + pA4.x, kAy = fA.y + pA4.y, kAz = fA.z + pA4.z, kAw = fA.w + pA4.w;
    float kBx = fB.x + pB4.x, kBy = fB.y + pB4.y, kBz = fB.z + pB4.z, kBw = fB.w + pB4.w;
    float pA[NHEAD], pB[NHEAD];
#pragma unroll
    for (int h = 0; h < NHEAD; h++) {
      pA[h] = kAx * qkr[h].x + kAy * qkr[h].y + kAz * qkr[h].z + kAw * qkr[h].w;
      pB[h] = kBx * qkr[h].x + kBy * qkr[h].y + kBz * qkr[h].z + kBw * qkr[h].w;
    }
    float rA = reduce8x64(pA, lane);
    float rB = reduce8x64(pB, lane);
    if ((lane & 7) == 0) {
      int h = (lane >> 3) & 7;
      aff[h][n]  = rA + qbk_s[h];
      aff[h][n2] = rB + qbk_s[h];
    }
  }
  __syncthreads();

  // phase S: softmax (waves 0-7, head==wave) || aff2 mean+stats (waves 8-15)
  if (wave < NHEAD) {
    int h = wave;
    float m = -3.0e38f;
    for (int n = lane; n < NPOS; n += 64) m = fmaxf(m, aff[h][n]);
#pragma unroll
    for (int off = 32; off >= 1; off >>= 1) m = fmaxf(m, __shfl_xor(m, off, 64));
    float sum = 0.f;
    for (int n = lane; n < NPOS; n += 64) {
      float e = __expf(aff[h][n] - m);
      wgt[h][n] = e;
      sum += e;
    }
#pragma unroll
    for (int off = 32; off >= 1; off >>= 1) sum += __shfl_xor(sum, off, 64);
    if (lane == 0) sinv[h] = 1.0f / sum;
  } else {
    int idx = t - 512;  // 0..511
    float ls = 0.f, lq = 0.f;
    {
      float a = 0.f;
#pragma unroll
      for (int h = 0; h < NHEAD; h++) a += aff[h][idx];
      a *= (1.0f / NHEAD);
      aff2s[idx] = a;
      ls += a; lq += a * a;
    }
    if (idx < NSEL - NPOS) {  // 256 more
      int n = idx + 512;
      float a = 0.f;
#pragma unroll
      for (int h = 0; h < NHEAD; h++) a += aff[h][n];
      a *= (1.0f / NHEAD);
      aff2s[n] = a;
      ls += a; lq += a * a;
    }
#pragma unroll
    for (int off = 32; off >= 1; off >>= 1) { ls += __shfl_xor(ls, off, 64); lq += __shfl_xor(lq, off, 64); }
    if (lane == 0) { redS[wave] = ls; redQ[wave] = lq; }
  }
  __syncthreads();

  {
    float tots = 0.f, totq = 0.f;
#pragma unroll
    for (int w2 = 8; w2 < 16; w2++) { tots += redS[w2]; totq += redQ[w2]; }
    float mean = tots * (1.0f / NSEL);
    float var = totq * (1.0f / NSEL) - mean * mean;
    float rstd = rsqrtf(var + 1e-5f);
    if (t < NSEL) norm_aff[(size_t)t * NSLOT + s] = (aff2s[t] - mean) * rstd;
  }

  // pass 2: read each f-row ONCE; every wave accumulates all 8 heads in registers
  {
    float acc[NHEAD][4];
#pragma unroll
    for (int h = 0; h < NHEAD; h++)
#pragma unroll
      for (int j = 0; j < 4; j++) acc[h][j] = 0.f;
    for (int n = wave; n < NPOS; n += NWAVE) {
      int idx = fsel[n];
      size_t base = ((size_t)idx * BB + bi) * D_ + (size_t)(lane * 4);
      const float4 fv = *(const float4*)(features + base);
#pragma unroll
      for (int h = 0; h < NHEAD; h++) {
        float w = wgt[h][n];   // LDS broadcast
        acc[h][0] += w * fv.x; acc[h][1] += w * fv.y;
        acc[h][2] += w * fv.z; acc[h][3] += w * fv.w;
      }
    }
#pragma unroll
    for (int hh = 0; hh < NHEAD; hh++) {
      int h = (hh + wave) & 7;  // stagger to spread bank pressure
      atomicAdd(&fbar[h][lane * 4 + 0], acc[h][0]);
      atomicAdd(&fbar[h][lane * 4 + 1], acc[h][1]);
      atomicAdd(&fbar[h][lane * 4 + 2], acc[h][2]);
      atomicAdd(&fbar[h][lane * 4 + 3], acc[h][3]);
    }
  }
  __syncthreads();

  // epilogue: out[o] = sinv[h]*(Wv[o,:].fbar[h]) + bv[o], 4-way split dot
  {
    int o = t >> 2, part = t & 3, h = o >> 5;
    const float4* wv = (const float4*)(ipw + (size_t)(2 * D_ + o) * D_ + part * 64);
    float a = 0.f;
#pragma unroll
    for (int i = 0; i < 16; i++) {
      float4 w4 = wv[i];
      int d = part * 64 + i * 4;
      a += fbar[h][d] * w4.x + fbar[h][d + 1] * w4.y + fbar[h][d + 2] * w4.z + fbar[h][d + 3] * w4.w;
    }
    float* pb = (float*)wgt;  // wgt dead now
    pb[o * 4 + part] = a;
  }
  __syncthreads();
  if (t < D_) {
    const float* pb = (const float*)wgt;
    float a = (pb[t * 4] + pb[t * 4 + 1] + pb[t * 4 + 2] + pb[t * 4 + 3]) * sinv[t >> 5] + ipb[2 * D_ + t];
    out_attn[s * D_ + t] = a;
  }
}

// ---------------- Kernel D: out-proj + residual + layernorm ----------------
__global__ __launch_bounds__(256) void epilogue_kernel(
    const float* __restrict__ slots, const float* __restrict__ out_attn,
    const float* __restrict__ wout, const float* __restrict__ bout,
    const float* __restrict__ lnw, const float* __restrict__ lnb,
    float* __restrict__ slots_new) {
  __shared__ float o[D_];
  __shared__ float redS[4], redQ[4];
  int s = blockIdx.x, t = threadIdx.x;
  int wave = t >> 6, lane = t & 63;
  o[t] = out_attn[s * D_ + t];
  __syncthreads();
  const float* w = wout + (size_t)t * D_;
  float a = bout[t];
  for (int d = 0; d < D_; d++) a += o[d] * w[d];
  float v = slots[s * D_ + t] + a;
  float ls = v, lq = v * v;
#pragma unroll
  for (int off = 32; off >= 1; off >>= 1) { ls += __shfl_xor(ls, off, 64); lq += __shfl_xor(lq, off, 64); }
  if (lane == 0) { redS[wave] = ls; redQ[wave] = lq; }
  __syncthreads();
  float tots = redS[0] + redS[1] + redS[2] + redS[3];
  float totq = redQ[0] + redQ[1] + redQ[2] + redQ[3];
  float mean = tots * (1.0f / D_);
  float var = totq * (1.0f / D_) - mean * mean;
  float rstd = rsqrtf(var + 1e-5f);
  slots_new[s * D_ + t] = (v - mean) * rstd * lnw[t] + lnb[t];
}

extern "C" void kernel_launch(void* const* d_in, const int* in_sizes, int n_in,
                              void* d_out, int out_size, void* d_ws, size_t ws_size,
                              hipStream_t stream) {
  const float* slots    = (const float*)d_in[0];
  const float* features = (const float*)d_in[1];
  const float* posenc   = (const float*)d_in[2];
  const float* curio    = (const float*)d_in[3];
  const int*   batch_idx= (const int*)d_in[4];
  const float* ipw      = (const float*)d_in[5];
  const float* ipb      = (const float*)d_in[6];
  const float* wout     = (const float*)d_in[7];
  const float* bout     = (const float*)d_in[8];
  const float* lnw      = (const float*)d_in[9];
  const float* lnb      = (const float*)d_in[10];

  char* ws = (char*)d_ws;
  int*   feat_sel = (int*)ws;                                   // 256*768*4   = 786432 B
  float* qk       = (float*)(ws + 786432);                      // 256*8*256*4 = 2097152 B
  float* qbk      = (float*)(ws + 786432 + 2097152);            // 256*8*4     = 8192 B
  float* out_attn = (float*)(ws + 786432 + 2097152 + 8192);     // 256*256*4   = 262144 B
  float* out_f    = (float*)d_out;                              // [0,65536) slots_new, [65536,262144) norm_aff

  topk_kernel<<<NSLOT, 1024, 0, stream>>>(curio, feat_sel);
  qproj_kernel<<<NSLOT, 256, 0, stream>>>(slots, ipw, ipb, qk, qbk);
  attn_kernel<<<NSLOT, 1024, 0, stream>>>(features, posenc, batch_idx, feat_sel,
                                          qk, qbk, ipw, ipb, out_attn, out_f + 65536);
  epilogue_kernel<<<NSLOT, 256, 0, stream>>>(slots, out_attn, wout, bout, lnw, lnb, out_f);
}

// Round 3
// 179.488 us; speedup vs baseline: 1.6360x; 1.0608x over previous
//
#include <hip/hip_runtime.h>
#include <math.h>

#define NSLOT 256
#define HWN   16384
#define D_    256
#define BB    4
#define NSEL  768
#define NPOS  512
#define NHEAD 8
#define AFFP  772

// Reduce 8 per-lane values over all 64 lanes simultaneously.
// Returns: full 64-lane sum of p[h], where h = (lane>>3)&7 for this lane.
__device__ __forceinline__ float reduce8x64(const float p[8], int lane) {
  float v[4];
#pragma unroll
  for (int h = 0; h < 4; h++) {
    float keep = (lane & 32) ? p[h + 4] : p[h];
    float send = (lane & 32) ? p[h] : p[h + 4];
    v[h] = keep + __shfl_xor(send, 32, 64);
  }
  float w[2];
#pragma unroll
  for (int h = 0; h < 2; h++) {
    float keep = (lane & 16) ? v[h + 2] : v[h];
    float send = (lane & 16) ? v[h] : v[h + 2];
    w[h] = keep + __shfl_xor(send, 16, 64);
  }
  float r;
  {
    float keep = (lane & 8) ? w[1] : w[0];
    float send = (lane & 8) ? w[0] : w[1];
    r = keep + __shfl_xor(send, 8, 64);
  }
  r += __shfl_xor(r, 4, 64);
  r += __shfl_xor(r, 2, 64);
  r += __shfl_xor(r, 1, 64);
  return r;
}

// ---------------- Kernel A: per-slot top-768 stable select (1024 thr) ----------------
__global__ __launch_bounds__(1024) void topk_kernel(const float* __restrict__ curio,
                                                    int* __restrict__ feat_sel) {
  __shared__ unsigned int hist[4096];
  __shared__ unsigned int wsum[16];
  __shared__ unsigned long long skey[2048];
  __shared__ int sBstar;
  __shared__ unsigned int sCount;
  int s = blockIdx.x;
  int t = threadIdx.x;
  int wave = t >> 6, lane = t & 63;
  const float* row = curio + (size_t)s * HWN;

  for (int i = t; i < 4096; i += 1024) hist[i] = 0;
  if (t == 0) sCount = 0;
  __syncthreads();
  for (int j = t; j < HWN; j += 1024) {
    unsigned int bits = __float_as_uint(row[j]);   // values in [0,1): bits monotone
    atomicAdd(&hist[bits >> 18], 1u);
  }
  __syncthreads();
  unsigned int cs = hist[t * 4] + hist[t * 4 + 1] + hist[t * 4 + 2] + hist[t * 4 + 3];
  unsigned int v = cs;
#pragma unroll
  for (int off = 1; off < 64; off <<= 1) {
    unsigned int u = __shfl_down(v, off, 64);
    if (lane + off < 64) v += u;       // suffix over lanes >= lane (this wave)
  }
  if (lane == 0) wsum[wave] = v;
  __syncthreads();
  unsigned int above = 0;
  for (int w2 = wave + 1; w2 < 16; w2++) above += wsum[w2];
  unsigned int sufAfter = above + (v - cs);
  if (sufAfter < NSEL && sufAfter + cs >= NSEL) {
    unsigned int local = sufAfter;
    for (int b = t * 4 + 3; b >= t * 4; b--) {
      unsigned int c = hist[b];
      if (local + c >= NSEL) { sBstar = b; break; }
      local += c;
    }
  }
  __syncthreads();
  int bstar = sBstar;
  for (int j = t; j < HWN; j += 1024) {
    unsigned int bits = __float_as_uint(row[j]);
    if ((int)(bits >> 18) >= bstar) {
      unsigned int pos = atomicAdd(&sCount, 1u);
      if (pos < 2048)
        skey[pos] = ((unsigned long long)bits << 14) | (unsigned long long)(16383 - j);
    }
  }
  __syncthreads();
  unsigned int M = sCount;
  int SZ = (M <= 1024) ? 1024 : 2048;
  for (int i = t; i < SZ; i += 1024) if (i >= (int)M) skey[i] = 0ull;
  for (int k = 2; k <= SZ; k <<= 1) {
    for (int j2 = k >> 1; j2 > 0; j2 >>= 1) {
      __syncthreads();
      for (int i = t; i < SZ; i += 1024) {
        int l = i ^ j2;
        if (l > i) {
          unsigned long long a = skey[i], b = skey[l];
          bool dir = ((i & k) == 0);
          if ((a < b) == dir) { skey[i] = b; skey[l] = a; }
        }
      }
    }
  }
  __syncthreads();
  for (int r = t; r < NSEL; r += 1024)
    feat_sel[s * NSEL + r] = 16383 - (int)(skey[r] & 16383ull);
}

// ---------------- Mega kernel: qproj + gather/aff + online-softmax PV + norm_aff
// ----------------               + Wv + out-proj + residual LN, all per slot ----------------
__global__ __launch_bounds__(1024) void mega_kernel(
    const float* __restrict__ slots, const float* __restrict__ features,
    const float* __restrict__ posenc, const int* __restrict__ batch_idx,
    const int* __restrict__ feat_sel,
    const float* __restrict__ ipw, const float* __restrict__ ipb,
    const float* __restrict__ wout, const float* __restrict__ bout,
    const float* __restrict__ lnw, const float* __restrict__ lnb,
    float* __restrict__ slots_new, float* __restrict__ norm_aff) {
  __shared__ float aff[NHEAD][AFFP];   // padded: bank-conflict-free 8-lane writes
  __shared__ float fbar[NHEAD][D_];
  __shared__ float qks[NHEAD][D_];
  __shared__ float aff2s[NSEL];
  __shared__ float srow[D_];
  __shared__ float qrow[D_];
  __shared__ float pq[1024];
  __shared__ float outv[D_];
  __shared__ float qbk_s[NHEAD], sinv[NHEAD], Mh[NHEAD];
  __shared__ float redS[16], redQ[16];

  int s = blockIdx.x, t = threadIdx.x;
  int wave = t >> 6, lane = t & 63;
  int bi = batch_idx[s];
  const int* fsel = feat_sel + s * NSEL;

  // P0: stage slot row, zero fbar
  if (t < 64) ((float4*)srow)[t] = ((const float4*)(slots + (size_t)s * D_))[t];
  for (int i = t; i < NHEAD * D_; i += 1024) ((float*)fbar)[i] = 0.f;
  __syncthreads();

  // P1: q = (Wq . srow + bq) * scaling   (quarter-dots, all 1024 threads)
  {
    int o = t >> 2, part = t & 3;
    const float4* w4 = (const float4*)(ipw + (size_t)o * D_ + part * 64);
    float a = 0.f;
#pragma unroll
    for (int i = 0; i < 16; i++) {
      float4 w = w4[i];
      int d = part * 64 + i * 4;
      a += srow[d] * w.x + srow[d + 1] * w.y + srow[d + 2] * w.z + srow[d + 3] * w.w;
    }
    pq[t] = a;
  }
  __syncthreads();
  if (t < D_)
    qrow[t] = (pq[t * 4] + pq[t * 4 + 1] + pq[t * 4 + 2] + pq[t * 4 + 3] + ipb[t]) *
              0.17677669529663689f;  // 1/sqrt(32)
  __syncthreads();

  // P2: qk[h][c] = sum_e qrow[h*32+e] * Wk[h*32+e][c]   (t<512: one float4 of c each)
  if (t < 512) {
    int h = t >> 6, c4 = t & 63;
    float4 a = {0.f, 0.f, 0.f, 0.f};
    const float4* wk = (const float4*)ipw + (size_t)(D_ + h * 32) * 64 + c4;
#pragma unroll
    for (int e = 0; e < 32; e++) {
      float q = qrow[h * 32 + e];
      float4 w = wk[(size_t)e * 64];
      a.x += q * w.x; a.y += q * w.y; a.z += q * w.z; a.w += q * w.w;
    }
    ((float4*)qks[h])[c4] = a;
  } else if (t < 520) {
    int h = t - 512;
    float a = 0.f;
    for (int e = 0; e < 32; e++) a += qrow[h * 32 + e] * ipb[D_ + h * 32 + e];
    qbk_s[h] = a;
  }
  __syncthreads();

  // P3: single-pass gather: aff for all 768 rows + online-softmax PV for pos rows
  float4 qkr[NHEAD];
#pragma unroll
  for (int h = 0; h < NHEAD; h++) qkr[h] = *(const float4*)&qks[h][lane * 4];
  float acc[NHEAD][4];
  float m[NHEAD];
#pragma unroll
  for (int h = 0; h < NHEAD; h++) {
    m[h] = -3.0e38f;
    acc[h][0] = acc[h][1] = acc[h][2] = acc[h][3] = 0.f;
  }

  for (int n = wave; n < NPOS; n += 32) {
    int n2 = n + 16;
    int idxA = fsel[n], idxB = fsel[n2];
    size_t baseA = ((size_t)idxA * BB + bi) * D_ + (size_t)(lane * 4);
    size_t baseB = ((size_t)idxB * BB + bi) * D_ + (size_t)(lane * 4);
    const float4 fA = *(const float4*)(features + baseA);
    const float4 pA4 = *(const float4*)(posenc + baseA);
    const float4 fB = *(const float4*)(features + baseB);
    const float4 pB4 = *(const float4*)(posenc + baseB);
    float kAx = fA.x + pA4.x, kAy = fA.y + pA4.y, kAz = fA.z + pA4.z, kAw = fA.w + pA4.w;
    float kBx = fB.x + pB4.x, kBy = fB.y + pB4.y, kBz = fB.z + pB4.z, kBw = fB.w + pB4.w;
    float dA[NHEAD], dB[NHEAD];
#pragma unroll
    for (int h = 0; h < NHEAD; h++) {
      dA[h] = kAx * qkr[h].x + kAy * qkr[h].y + kAz * qkr[h].z + kAw * qkr[h].w;
      dB[h] = kBx * qkr[h].x + kBy * qkr[h].y + kBz * qkr[h].z + kBw * qkr[h].w;
    }
    float rA = reduce8x64(dA, lane);
    float rB = reduce8x64(dB, lane);
    if ((lane & 7) == 0) {
      int h = lane >> 3;
      aff[h][n] = rA + qbk_s[h];
      aff[h][n2] = rB + qbk_s[h];
    }
    // online PV (bias-free weights; bias folded into final scale)
#pragma unroll
    for (int h = 0; h < NHEAD; h++) {
      float a = __shfl(rA, h * 8, 64);
      float mn = fmaxf(m[h], a);
      float w = __expf(a - mn);
      if (mn > m[h]) {
        float sc = __expf(m[h] - mn);
        acc[h][0] *= sc; acc[h][1] *= sc; acc[h][2] *= sc; acc[h][3] *= sc;
        m[h] = mn;
      }
      acc[h][0] += w * fA.x; acc[h][1] += w * fA.y;
      acc[h][2] += w * fA.z; acc[h][3] += w * fA.w;
    }
#pragma unroll
    for (int h = 0; h < NHEAD; h++) {
      float a = __shfl(rB, h * 8, 64);
      float mn = fmaxf(m[h], a);
      float w = __expf(a - mn);
      if (mn > m[h]) {
        float sc = __expf(m[h] - mn);
        acc[h][0] *= sc; acc[h][1] *= sc; acc[h][2] *= sc; acc[h][3] *= sc;
        m[h] = mn;
      }
      acc[h][0] += w * fB.x; acc[h][1] += w * fB.y;
      acc[h][2] += w * fB.z; acc[h][3] += w * fB.w;
    }
  }
  // neg rows: aff only
  for (int n = NPOS + wave; n < NSEL; n += 32) {
    int n2 = n + 16;
    int idxA = fsel[n], idxB = fsel[n2];
    size_t baseA = ((size_t)idxA * BB + bi) * D_ + (size_t)(lane * 4);
    size_t baseB = ((size_t)idxB * BB + bi) * D_ + (size_t)(lane * 4);
    const float4 fA = *(const float4*)(features + baseA);
    const float4 pA4 = *(const float4*)(posenc + baseA);
    const float4 fB = *(const float4*)(features + baseB);
    const float4 pB4 = *(const float4*)(posenc + baseB);
    float kAx = fA.x + pA4.x, kAy = fA.y + pA4.y, kAz = fA.z + pA4.z, kAw = fA.w + pA4.w;
    float kBx = fB.x + pB4.x, kBy = fB.y + pB4.y, kBz = fB.z + pB4.z, kBw = fB.w + pB4.w;
    float dA[NHEAD], dB[NHEAD];
#pragma unroll
    for (int h = 0; h < NHEAD; h++) {
      dA[h] = kAx * qkr[h].x + kAy * qkr[h].y + kAz * qkr[h].z + kAw * qkr[h].w;
      dB[h] = kBx * qkr[h].x + kBy * qkr[h].y + kBz * qkr[h].z + kBw * qkr[h].w;
    }
    float rA = reduce8x64(dA, lane);
    float rB = reduce8x64(dB, lane);
    if ((lane & 7) == 0) {
      int h = lane >> 3;
      aff[h][n] = rA + qbk_s[h];
      aff[h][n2] = rB + qbk_s[h];
    }
  }
  __syncthreads();

  // P4: softmax max+denominator (waves 0-7) || aff2 mean + LN stats (waves 8-15)
  if (wave < NHEAD) {
    int h = wave;
    float mx = -3.0e38f;
    for (int n = lane; n < NPOS; n += 64) mx = fmaxf(mx, aff[h][n]);
#pragma unroll
    for (int off = 32; off >= 1; off >>= 1) mx = fmaxf(mx, __shfl_xor(mx, off, 64));
    float sum = 0.f;
    for (int n = lane; n < NPOS; n += 64) sum += __expf(aff[h][n] - mx);
#pragma unroll
    for (int off = 32; off >= 1; off >>= 1) sum += __shfl_xor(sum, off, 64);
    if (lane == 0) { Mh[h] = mx; sinv[h] = 1.0f / sum; }
  } else {
    int idx = t - 512;  // 0..511
    float ls = 0.f, lq = 0.f;
    {
      float a = 0.f;
#pragma unroll
      for (int h = 0; h < NHEAD; h++) a += aff[h][idx];
      a *= (1.0f / NHEAD);
      aff2s[idx] = a;
      ls += a; lq += a * a;
    }
    if (idx < NSEL - NPOS) {
      int n = idx + NPOS;
      float a = 0.f;
#pragma unroll
      for (int h = 0; h < NHEAD; h++) a += aff[h][n];
      a *= (1.0f / NHEAD);
      aff2s[n] = a;
      ls += a; lq += a * a;
    }
#pragma unroll
    for (int off = 32; off >= 1; off >>= 1) { ls += __shfl_xor(ls, off, 64); lq += __shfl_xor(lq, off, 64); }
    if (lane == 0) { redS[wave] = ls; redQ[wave] = lq; }
  }
  __syncthreads();

  // P5: norm_aff write + cross-wave fbar combine (scaled by exp(m+qbk-M))
  {
    float tots = 0.f, totq = 0.f;
#pragma unroll
    for (int w2 = 8; w2 < 16; w2++) { tots += redS[w2]; totq += redQ[w2]; }
    float mean = tots * (1.0f / NSEL);
    float var = totq * (1.0f / NSEL) - mean * mean;
    float rstd = rsqrtf(var + 1e-5f);
    if (t < NSEL) norm_aff[(size_t)t * NSLOT + s] = (aff2s[t] - mean) * rstd;
  }
#pragma unroll
  for (int h = 0; h < NHEAD; h++) {
    float sc = __expf(m[h] + qbk_s[h] - Mh[h]);
    atomicAdd(&fbar[h][lane * 4 + 0], acc[h][0] * sc);
    atomicAdd(&fbar[h][lane * 4 + 1], acc[h][1] * sc);
    atomicAdd(&fbar[h][lane * 4 + 2], acc[h][2] * sc);
    atomicAdd(&fbar[h][lane * 4 + 3], acc[h][3] * sc);
  }
  __syncthreads();

  // P6: out = sinv[h]*(Wv . fbar[h]) + bv   (quarter-dots)
  {
    int o = t >> 2, part = t & 3, h = o >> 5;
    const float4* wv = (const float4*)(ipw + (size_t)(2 * D_ + o) * D_ + part * 64);
    float a = 0.f;
#pragma unroll
    for (int i = 0; i < 16; i++) {
      float4 w = wv[i];
      int d = part * 64 + i * 4;
      a += fbar[h][d] * w.x + fbar[h][d + 1] * w.y + fbar[h][d + 2] * w.z + fbar[h][d + 3] * w.w;
    }
    pq[t] = a;
  }
  __syncthreads();
  if (t < D_)
    outv[t] = (pq[t * 4] + pq[t * 4 + 1] + pq[t * 4 + 2] + pq[t * 4 + 3]) * sinv[t >> 5] +
              ipb[2 * D_ + t];
  __syncthreads();

  // P7: slots_new = LN(srow + Wout.outv + bout) * lnw + lnb
  {
    int o = t >> 2, part = t & 3;
    const float4* w4 = (const float4*)(wout + (size_t)o * D_ + part * 64);
    float a = 0.f;
#pragma unroll
    for (int i = 0; i < 16; i++) {
      float4 w = w4[i];
      int d = part * 64 + i * 4;
      a += outv[d] * w.x + outv[d + 1] * w.y + outv[d + 2] * w.z + outv[d + 3] * w.w;
    }
    pq[t] = a;
  }
  __syncthreads();
  float v = 0.f;
  if (t < D_) {
    v = srow[t] + pq[t * 4] + pq[t * 4 + 1] + pq[t * 4 + 2] + pq[t * 4 + 3] + bout[t];
    float ls = v, lq = v * v;
#pragma unroll
    for (int off = 32; off >= 1; off >>= 1) { ls += __shfl_xor(ls, off, 64); lq += __shfl_xor(lq, off, 64); }
    if (lane == 0) { redS[wave] = ls; redQ[wave] = lq; }
  }
  __syncthreads();
  if (t < D_) {
    float tots = redS[0] + redS[1] + redS[2] + redS[3];
    float totq = redQ[0] + redQ[1] + redQ[2] + redQ[3];
    float mean = tots * (1.0f / D_);
    float var = totq * (1.0f / D_) - mean * mean;
    float rstd = rsqrtf(var + 1e-5f);
    slots_new[s * D_ + t] = (v - mean) * rstd * lnw[t] + lnb[t];
  }
}

extern "C" void kernel_launch(void* const* d_in, const int* in_sizes, int n_in,
                              void* d_out, int out_size, void* d_ws, size_t ws_size,
                              hipStream_t stream) {
  const float* slots    = (const float*)d_in[0];
  const float* features = (const float*)d_in[1];
  const float* posenc   = (const float*)d_in[2];
  const float* curio    = (const float*)d_in[3];
  const int*   batch_idx= (const int*)d_in[4];
  const float* ipw      = (const float*)d_in[5];
  const float* ipb      = (const float*)d_in[6];
  const float* wout     = (const float*)d_in[7];
  const float* bout     = (const float*)d_in[8];
  const float* lnw      = (const float*)d_in[9];
  const float* lnb      = (const float*)d_in[10];

  int* feat_sel = (int*)d_ws;                 // 256*768*4 = 786432 B
  float* out_f  = (float*)d_out;              // [0,65536) slots_new, [65536,262144) norm_aff

  topk_kernel<<<NSLOT, 1024, 0, stream>>>(curio, feat_sel);
  mega_kernel<<<NSLOT, 1024, 0, stream>>>(slots, features, posenc, batch_idx, feat_sel,
                                          ipw, ipb, wout, bout, lnw, lnb,
                                          out_f, out_f + 65536);
}